// Round 3
// baseline (233.100 us; speedup 1.0000x reference)
//
#include <hip/hip_runtime.h>
#include <cstdint>
#include <cstddef>

// LSTM cell on MI355X. Inputs f32, OUTPUTS f32 (h then C, concatenated flat).
// Phase 1: pack x|hx -> A_ws [8192][2048] bf16, Wx|Wh -> B_ws [4096][2048] bf16 (d_ws).
// Phase 2: fused MFMA GEMM (m97 structure): gates = A_ws @ B_ws^T (+biases) with the
//   block's 128 N-cols remapped as waveN(2) x gate(4) x hcol(16) so each lane holds all
//   4 gates for its (row,hcol) -> lane-local LSTM epilogue, no gate matrix materialized.
// Fallback (ws too small): naive vector-f32 kernel, correct but slow.

using bf16x8  = __attribute__((ext_vector_type(8))) __bf16;
using f32x4   = __attribute__((ext_vector_type(4))) float;
using ushort8 = __attribute__((ext_vector_type(8))) unsigned short;

__device__ __forceinline__ unsigned short f2bf(float f) {
  union { float f; unsigned int i; } v; v.f = f;
  unsigned int x = v.i;
  return (unsigned short)((x + 0x7fffu + ((x >> 16) & 1u)) >> 16);  // RNE
}
__device__ __forceinline__ float sigm(float x)   { return 1.0f / (1.0f + __expf(-x)); }
__device__ __forceinline__ float tanh_f(float x) { return 1.0f - 2.0f / (__expf(2.0f * x) + 1.0f); }

__device__ __forceinline__ void gload16(const void* g, void* l) {
  __builtin_amdgcn_global_load_lds(
      (const __attribute__((address_space(1))) void*)g,
      (__attribute__((address_space(3))) void*)l, 16, 0, 0);
}

#define B_DIM 8192
#define H_DIM 1024

// ---- Phase 1: pack [s0|s1] rows of 1024 f32 each -> dst [rows][2048] bf16 ----
__global__ __launch_bounds__(256) void pack2_bf16(
    const float* __restrict__ s0, const float* __restrict__ s1,
    unsigned short* __restrict__ dst, long total_chunks) {
  const long stride = (long)gridDim.x * blockDim.x;
  for (long idx = (long)blockIdx.x * blockDim.x + threadIdx.x; idx < total_chunks; idx += stride) {
    const long row = idx >> 8;            // 256 8-elem chunks per 2048-col row
    const int  k   = (int)(idx & 255) * 8;
    const float* src = (k < 1024) ? (s0 + row * 1024 + k) : (s1 + row * 1024 + (k - 1024));
    const f32x4 v0 = *(const f32x4*)src;
    const f32x4 v1 = *(const f32x4*)(src + 4);
    ushort8 o;
    o[0] = f2bf(v0[0]); o[1] = f2bf(v0[1]); o[2] = f2bf(v0[2]); o[3] = f2bf(v0[3]);
    o[4] = f2bf(v1[0]); o[5] = f2bf(v1[1]); o[6] = f2bf(v1[2]); o[7] = f2bf(v1[3]);
    *(ushort8*)(dst + idx * 8) = o;
  }
}

// ---- Phase 2: fused GEMM + LSTM epilogue ----
__global__ __launch_bounds__(256) void lstm_fused_gemm(
    const unsigned short* __restrict__ Aws,   // [8192][2048] bf16
    const unsigned short* __restrict__ Bws,   // [4096][2048] bf16 (row g = gate*1024+h)
    const float* __restrict__ cxp, const float* __restrict__ bxp,
    const float* __restrict__ bhp, float* __restrict__ outp)
{
  __shared__ __attribute__((aligned(16))) unsigned short As[128 * 64];
  __shared__ __attribute__((aligned(16))) unsigned short Bs[128 * 64];

  const int tid   = threadIdx.x;
  const int l     = tid & 63;
  const int w     = tid >> 6;
  const int waveM = w >> 1;        // which 64 batch rows
  const int waveN = w & 1;         // which 16 hcols
  const int m0    = blockIdx.x * 128;
  const int h0    = blockIdx.y * 32;

  const int c  = l & 15;
  const int q  = l >> 4;
  const int kq = q * 8;

  f32x4 acc[4][4];
#pragma unroll
  for (int mi = 0; mi < 4; ++mi)
#pragma unroll
    for (int ni = 0; ni < 4; ++ni) acc[mi][ni] = (f32x4){0.f, 0.f, 0.f, 0.f};

  for (int kt = 0; kt < 32; ++kt) {
    const int k0 = kt * 64;
    // Stage A: 128 rows x 64 bf16 = 1024 16B-chunks, 4/thread.
#pragma unroll
    for (int it = 0; it < 4; ++it) {
      const int fc  = tid + it * 256;
      const int row = fc >> 3, ch = fc & 7;
      gload16(Aws + (size_t)(m0 + row) * 2048 + k0 + ch * 8, &As[fc * 8]);
    }
    // Stage B with gate remap: LDS row ln = waveN*64 + gate*16 + hsub
    //   -> W row = gate*1024 + h0 + waveN*16 + hsub.
#pragma unroll
    for (int it = 0; it < 4; ++it) {
      const int fc  = tid + it * 256;
      const int ln  = fc >> 3, ch = fc & 7;
      const int grow = ((ln >> 4) & 3) * 1024 + h0 + (ln >> 6) * 16 + (ln & 15);
      gload16(Bws + (size_t)grow * 2048 + k0 + ch * 8, &Bs[fc * 8]);
    }
    __syncthreads();

#pragma unroll
    for (int kk = 0; kk < 2; ++kk) {
      bf16x8 a[4], b[4];
#pragma unroll
      for (int mi = 0; mi < 4; ++mi)
        a[mi] = *(const bf16x8*)&As[(waveM * 64 + mi * 16 + c) * 64 + kk * 32 + kq];
#pragma unroll
      for (int ni = 0; ni < 4; ++ni)
        b[ni] = *(const bf16x8*)&Bs[(waveN * 64 + ni * 16 + c) * 64 + kk * 32 + kq];
#pragma unroll
      for (int mi = 0; mi < 4; ++mi)
#pragma unroll
        for (int ni = 0; ni < 4; ++ni)
          acc[mi][ni] = __builtin_amdgcn_mfma_f32_16x16x32_bf16(a[mi], b[ni], acc[mi][ni], 0, 0, 0);
    }
    __syncthreads();
  }

  // Epilogue: D layout col=lane&15 (hcol), row=(lane>>4)*4+j (batch). ni = gate.
  const int hcol = h0 + waveN * 16 + c;
  const float bias0 = bxp[hcol]        + bhp[hcol];
  const float bias1 = bxp[1024 + hcol] + bhp[1024 + hcol];
  const float bias2 = bxp[2048 + hcol] + bhp[2048 + hcol];
  const float bias3 = bxp[3072 + hcol] + bhp[3072 + hcol];
  float* __restrict__ hOut = outp;
  float* __restrict__ cOut = outp + (size_t)B_DIM * H_DIM;

#pragma unroll
  for (int mi = 0; mi < 4; ++mi) {
#pragma unroll
    for (int j = 0; j < 4; ++j) {
      const int row = m0 + waveM * 64 + mi * 16 + q * 4 + j;
      const float ff = sigm(acc[mi][0][j] + bias0);
      const float ii = sigm(acc[mi][1][j] + bias1);
      const float gg = tanh_f(acc[mi][2][j] + bias2);
      const float oo = sigm(acc[mi][3][j] + bias3);
      const int off  = row * H_DIM + hcol;
      const float Cv = ff * cxp[off] + ii * gg;
      const float hv = oo * tanh_f(Cv);
      hOut[off] = hv;
      cOut[off] = Cv;
    }
  }
}

// ---- Fallback: correct naive vector kernel (only if d_ws too small) ----
__global__ __launch_bounds__(256) void lstm_fallback(
    const float* __restrict__ xp,  const float* __restrict__ hxp,
    const float* __restrict__ cxp, const float* __restrict__ wxp,
    const float* __restrict__ whp, const float* __restrict__ bxp,
    const float* __restrict__ bhp, float* __restrict__ outp)
{
  const int idx = blockIdx.x * 256 + threadIdx.x;   // one (row, hcol) per thread
  const int row = idx >> 10, col = idx & 1023;
  float g[4] = {0.f, 0.f, 0.f, 0.f};
  for (int k = 0; k < 1024; ++k) {
    const float xv = xp[row * 1024 + k];
    const float hv = hxp[row * 1024 + k];
#pragma unroll
    for (int gi = 0; gi < 4; ++gi)
      g[gi] += xv * wxp[(gi * 1024 + col) * 1024 + k] + hv * whp[(gi * 1024 + col) * 1024 + k];
  }
  const float ff = sigm(g[0] + bxp[col]          + bhp[col]);
  const float ii = sigm(g[1] + bxp[1024 + col] + bhp[1024 + col]);
  const float gg = tanh_f(g[2] + bxp[2048 + col] + bhp[2048 + col]);
  const float oo = sigm(g[3] + bxp[3072 + col] + bhp[3072 + col]);
  const float Cv = ff * cxp[idx] + ii * gg;
  const float hv = oo * tanh_f(Cv);
  outp[idx] = hv;
  outp[(size_t)B_DIM * H_DIM + idx] = Cv;
}

extern "C" void kernel_launch(void* const* d_in, const int* in_sizes, int n_in,
                              void* d_out, int out_size, void* d_ws, size_t ws_size,
                              hipStream_t stream) {
  const float* xp  = (const float*)d_in[0];
  const float* hxp = (const float*)d_in[1];
  const float* cxp = (const float*)d_in[2];
  const float* wxp = (const float*)d_in[3];
  const float* whp = (const float*)d_in[4];
  const float* bxp = (const float*)d_in[5];
  const float* bhp = (const float*)d_in[6];
  float* outp = (float*)d_out;

  const size_t A_elems = (size_t)B_DIM * 2048;   // 16.78M
  const size_t B_elems = (size_t)4096  * 2048;   //  8.39M
  if (ws_size >= (A_elems + B_elems) * sizeof(unsigned short)) {
    unsigned short* Aws = (unsigned short*)d_ws;
    unsigned short* Bws = Aws + A_elems;
    pack2_bf16<<<2048, 256, 0, stream>>>(xp,  hxp, Aws, (long)(A_elems / 8));
    pack2_bf16<<<2048, 256, 0, stream>>>(wxp, whp, Bws, (long)(B_elems / 8));
    dim3 grid(B_DIM / 128, H_DIM / 32);
    lstm_fused_gemm<<<grid, 256, 0, stream>>>(Aws, Bws, cxp, bxp, bhp, outp);
  } else {
    lstm_fallback<<<(B_DIM * H_DIM) / 256, 256, 0, stream>>>(
        xp, hxp, cxp, wxp, whp, bxp, bhp, outp);
  }
}

// Round 4
// 215.847 us; speedup vs baseline: 1.0799x; 1.0799x over previous
//
#include <hip/hip_runtime.h>
#include <cstdint>
#include <cstddef>

// LSTM cell on MI355X. f32 in, f32 out (h then C).
// Phase 1: pack x|hx -> A_ws [8192][2048] bf16 ; Wx|Wh -> B_ws [4096][2048] bf16.
// Phase 2: 256x256 (BMxBN) BK=64 MFMA GEMM, 8 waves (2Mx4N), counted-vmcnt deep
//   pipeline (vmcnt(8)/vmcnt(4), never 0 in steady state), kk-split LDS halves,
//   XOR slot swizzle (4-way max conflicts), setprio around MFMA clusters,
//   XCD-aware block swizzle. N-cols remapped waveN(4) x gate(4) x hcol(16) so each
//   lane holds all 4 gates for its (row,hcol) -> lane-local LSTM epilogue.

using bf16x8  = __attribute__((ext_vector_type(8))) __bf16;
using f32x4   = __attribute__((ext_vector_type(4))) float;
using ushort8 = __attribute__((ext_vector_type(8))) unsigned short;

__device__ __forceinline__ unsigned short f2bf(float f) {
  union { float f; unsigned int i; } v; v.f = f;
  unsigned int x = v.i;
  return (unsigned short)((x + 0x7fffu + ((x >> 16) & 1u)) >> 16);  // RNE
}
__device__ __forceinline__ float sigm(float x)   { return 1.0f / (1.0f + __expf(-x)); }
__device__ __forceinline__ float tanh_f(float x) { return 1.0f - 2.0f / (__expf(2.0f * x) + 1.0f); }

__device__ __forceinline__ void gload16(const void* g, void* l) {
  __builtin_amdgcn_global_load_lds(
      (const __attribute__((address_space(1))) void*)g,
      (__attribute__((address_space(3))) void*)l, 16, 0, 0);
}

#define B_DIM 8192
#define H_DIM 1024
#define NT 32   // K=2048 / BK=64

// ---- Phase 1: pack [s0|s1] rows of 1024 f32 each -> dst [rows][2048] bf16 ----
__global__ __launch_bounds__(256) void pack2_bf16(
    const float* __restrict__ s0, const float* __restrict__ s1,
    unsigned short* __restrict__ dst, long total_chunks) {
  const long stride = (long)gridDim.x * blockDim.x;
  for (long idx = (long)blockIdx.x * blockDim.x + threadIdx.x; idx < total_chunks; idx += stride) {
    const long row = idx >> 8;
    const int  k   = (int)(idx & 255) * 8;
    const float* src = (k < 1024) ? (s0 + row * 1024 + k) : (s1 + row * 1024 + (k - 1024));
    const f32x4 v0 = *(const f32x4*)src;
    const f32x4 v1 = *(const f32x4*)(src + 4);
    ushort8 o;
    o[0] = f2bf(v0[0]); o[1] = f2bf(v0[1]); o[2] = f2bf(v0[2]); o[3] = f2bf(v0[3]);
    o[4] = f2bf(v1[0]); o[5] = f2bf(v1[1]); o[6] = f2bf(v1[2]); o[7] = f2bf(v1[3]);
    *(ushort8*)(dst + idx * 8) = o;
  }
}

// ---- Phase 2: deep-pipelined 256^2 GEMM + LSTM epilogue ----
__global__ __launch_bounds__(512, 2) void lstm_gemm256(
    const unsigned short* __restrict__ Aws,   // [8192][2048] bf16
    const unsigned short* __restrict__ Bws,   // [4096][2048] bf16 (row = gate*1024+h)
    const float* __restrict__ cxp, const float* __restrict__ bxp,
    const float* __restrict__ bhp, float* __restrict__ outp)
{
  // [dbuf][kk-half][256 rows][32 bf16]  (A: 64KB, B: 64KB)
  __shared__ __attribute__((aligned(16))) unsigned short As[2][2][256 * 32];
  __shared__ __attribute__((aligned(16))) unsigned short Bs[2][2][256 * 32];

  const int tid = threadIdx.x;
  const int l   = tid & 63, w = tid >> 6;
  const int wm  = w >> 2;          // 0..1 : which 128 batch rows
  const int wn  = w & 3;           // 0..3 : which 16 hcols
  const int c   = l & 15, q = l >> 4;
  const int sw  = (q ^ (c & 3)) * 8;   // swizzled k-slot (elements), lane-constant

  // XCD-aware swizzle: 512 blocks, 8 XCDs, 64 tiles/XCD, nb-major in-chunk
  const int bid  = blockIdx.x;
  const int tile = (bid & 7) * 64 + (bid >> 3);
  const int mb   = tile & 31, nb = tile >> 5;
  const int m0   = mb * 256, h0 = nb * 64;

  f32x4 acc[8][4];
#pragma unroll
  for (int mi = 0; mi < 8; ++mi)
#pragma unroll
    for (int ni = 0; ni < 4; ++ni) acc[mi][ni] = (f32x4){0.f, 0.f, 0.f, 0.f};

  // Stage one kk-half of A/B for tile t into buf. Issue order inside a tile:
  // [A kk0, B kk0] sched_barrier [A kk1, B kk1]  -> vmcnt counts groups of 4.
  auto stageA = [&](int buf, int kk, int t) {
#pragma unroll
    for (int it = 0; it < 2; ++it) {
      const int fcx = tid + it * 512;
      const int row = fcx >> 2, chq = fcx & 3;
      gload16(Aws + (size_t)(m0 + row) * 2048 + t * 64 + kk * 32 + ((chq ^ (row & 3)) * 8),
              &As[buf][kk][fcx * 8]);
    }
  };
  auto stageB = [&](int buf, int kk, int t) {
#pragma unroll
    for (int it = 0; it < 2; ++it) {
      const int fcx = tid + it * 512;
      const int row = fcx >> 2, chq = fcx & 3;
      const int grow = ((row >> 4) & 3) * 1024 + h0 + (row >> 6) * 16 + (row & 15);
      gload16(Bws + (size_t)grow * 2048 + t * 64 + kk * 32 + ((chq ^ (row & 3)) * 8),
              &Bs[buf][kk][fcx * 8]);
    }
  };

  // One K-half: 4 b-frags + 2x(4 a-frags, 16 MFMA)
  auto halfK = [&](int buf, int kk) {
    const unsigned short* Ab = &As[buf][kk][0];
    const unsigned short* Bb = &Bs[buf][kk][0];
    bf16x8 b[4];
#pragma unroll
    for (int ni = 0; ni < 4; ++ni)
      b[ni] = *(const bf16x8*)&Bb[(wn * 64 + ni * 16 + c) * 32 + sw];
#pragma unroll
    for (int mh = 0; mh < 2; ++mh) {
      bf16x8 a[4];
#pragma unroll
      for (int i = 0; i < 4; ++i)
        a[i] = *(const bf16x8*)&Ab[(wm * 128 + mh * 64 + i * 16 + c) * 32 + sw];
      __builtin_amdgcn_s_setprio(1);
#pragma unroll
      for (int i = 0; i < 4; ++i)
#pragma unroll
        for (int ni = 0; ni < 4; ++ni)
          acc[mh * 4 + i][ni] =
              __builtin_amdgcn_mfma_f32_16x16x32_bf16(a[i], b[ni], acc[mh * 4 + i][ni], 0, 0, 0);
      __builtin_amdgcn_s_setprio(0);
    }
  };

  // Prologue: stage tile 0 into buf0; kk0 drained, kk1 left in flight (4).
  stageA(0, 0, 0); stageB(0, 0, 0);
  __builtin_amdgcn_sched_barrier(0);
  stageA(0, 1, 0); stageB(0, 1, 0);
  asm volatile("s_waitcnt vmcnt(4)" ::: "memory");
  __builtin_amdgcn_s_barrier();

  // Steady state invariant entering tile t: kk1(t) in flight (4 loads).
  for (int t = 0; t < NT - 1; ++t) {
    const int cur = t & 1, nxt = cur ^ 1;
    stageA(nxt, 0, t + 1); stageB(nxt, 0, t + 1);
    __builtin_amdgcn_sched_barrier(0);
    stageA(nxt, 1, t + 1); stageB(nxt, 1, t + 1);
    halfK(cur, 0);
    asm volatile("s_waitcnt vmcnt(8)" ::: "memory");  // kk1(t) landed
    __builtin_amdgcn_s_barrier();
    halfK(cur, 1);
    asm volatile("s_waitcnt vmcnt(4)" ::: "memory");  // kk0(t+1) landed
    __builtin_amdgcn_s_barrier();
  }
  // Last tile (no prefetch)
  halfK((NT - 1) & 1, 0);
  asm volatile("s_waitcnt vmcnt(0)" ::: "memory");    // kk1(last) landed
  __builtin_amdgcn_s_barrier();
  halfK((NT - 1) & 1, 1);

  // Epilogue: acc[mi][gate][j]; D layout col=lane&15 -> hcol, row=(lane>>4)*4+j.
  const int hcol = h0 + wn * 16 + c;
  float bias[4];
#pragma unroll
  for (int g = 0; g < 4; ++g) bias[g] = bxp[g * 1024 + hcol] + bhp[g * 1024 + hcol];
  float* __restrict__ hOut = outp;
  float* __restrict__ cOut = outp + (size_t)B_DIM * H_DIM;

#pragma unroll
  for (int mi = 0; mi < 8; ++mi) {
#pragma unroll
    for (int j = 0; j < 4; ++j) {
      const int row = m0 + wm * 128 + mi * 16 + q * 4 + j;
      const float ff = sigm(acc[mi][0][j] + bias[0]);
      const float ii = sigm(acc[mi][1][j] + bias[1]);
      const float gg = tanh_f(acc[mi][2][j] + bias[2]);
      const float oo = sigm(acc[mi][3][j] + bias[3]);
      const int off  = row * H_DIM + hcol;
      const float Cv = ff * cxp[off] + ii * gg;
      const float hv = oo * tanh_f(Cv);
      hOut[off] = hv;
      cOut[off] = Cv;
    }
  }
}

// ---- Fallback: correct naive vector kernel (only if d_ws too small) ----
__global__ __launch_bounds__(256) void lstm_fallback(
    const float* __restrict__ xp,  const float* __restrict__ hxp,
    const float* __restrict__ cxp, const float* __restrict__ wxp,
    const float* __restrict__ whp, const float* __restrict__ bxp,
    const float* __restrict__ bhp, float* __restrict__ outp)
{
  const int idx = blockIdx.x * 256 + threadIdx.x;
  const int row = idx >> 10, col = idx & 1023;
  float g[4] = {0.f, 0.f, 0.f, 0.f};
  for (int k = 0; k < 1024; ++k) {
    const float xv = xp[row * 1024 + k];
    const float hv = hxp[row * 1024 + k];
#pragma unroll
    for (int gi = 0; gi < 4; ++gi)
      g[gi] += xv * wxp[(gi * 1024 + col) * 1024 + k] + hv * whp[(gi * 1024 + col) * 1024 + k];
  }
  const float ff = sigm(g[0] + bxp[col]          + bhp[col]);
  const float ii = sigm(g[1] + bxp[1024 + col] + bhp[1024 + col]);
  const float gg = tanh_f(g[2] + bxp[2048 + col] + bhp[2048 + col]);
  const float oo = sigm(g[3] + bxp[3072 + col] + bhp[3072 + col]);
  const float Cv = ff * cxp[idx] + ii * gg;
  const float hv = oo * tanh_f(Cv);
  outp[idx] = hv;
  outp[(size_t)B_DIM * H_DIM + idx] = Cv;
}

extern "C" void kernel_launch(void* const* d_in, const int* in_sizes, int n_in,
                              void* d_out, int out_size, void* d_ws, size_t ws_size,
                              hipStream_t stream) {
  const float* xp  = (const float*)d_in[0];
  const float* hxp = (const float*)d_in[1];
  const float* cxp = (const float*)d_in[2];
  const float* wxp = (const float*)d_in[3];
  const float* whp = (const float*)d_in[4];
  const float* bxp = (const float*)d_in[5];
  const float* bhp = (const float*)d_in[6];
  float* outp = (float*)d_out;

  const size_t A_elems = (size_t)B_DIM * 2048;   // 16.78M
  const size_t B_elems = (size_t)4096  * 2048;   //  8.39M
  if (ws_size >= (A_elems + B_elems) * sizeof(unsigned short)) {
    unsigned short* Aws = (unsigned short*)d_ws;
    unsigned short* Bws = Aws + A_elems;
    pack2_bf16<<<2048, 256, 0, stream>>>(xp,  hxp, Aws, (long)(A_elems / 8));
    pack2_bf16<<<2048, 256, 0, stream>>>(wxp, whp, Bws, (long)(B_elems / 8));
    lstm_gemm256<<<512, 512, 0, stream>>>(Aws, Bws, cxp, bxp, bhp, outp);
  } else {
    lstm_fallback<<<(B_DIM * H_DIM) / 256, 256, 0, stream>>>(
        xp, hxp, cxp, wxp, whp, bxp, bhp, outp);
  }
}